// Round 7
// baseline (127.036 us; speedup 1.0000x reference)
//
#include <hip/hip_runtime.h>

// Problem constants
#define Bc  32
#define Nc  16
#define Tc  64
#define Hc  256
#define NTc 1024   // N*T

typedef unsigned short u16;
using v8s = __attribute__((ext_vector_type(8))) short;   // 8 bf16 = 4 VGPRs (MFMA A/B frag)
using v4f = __attribute__((ext_vector_type(4))) float;   // MFMA C/D frag

// fp32 -> bf16 round-to-nearest-even (bit manip; inputs finite)
static __device__ __forceinline__ u16 f2bf(float x) {
    unsigned u = __float_as_uint(x);
    unsigned r = u + 0x7fffu + ((u >> 16) & 1u);
    return (u16)(r >> 16);
}
static __device__ __forceinline__ float bf2f(u16 h) {
    return __uint_as_float(((unsigned)h) << 16);
}

// ---------------------------------------------------------------------------
// Fused kernel (v5 math, prep merged in via software per-b barrier):
//  head:  block (b,i), wave w computes M row t=4i+w (sum over 16 i', /16),
//         writes MT[b][h][4i..4i+4) via agent-scope 8B stores, then
//         release-signals cnt[b]. XCD swizzle clusters the 16 siblings of
//         each b -> X re-read in Phase A is an L2 hit; neigh crosses HBM
//         ~once (was twice with the separate prep kernel).
//  Phase A / softmax / Wpart: identical to the 104.7us-proven v5.
//  pre-Phase-B: thread0 acquire-spins cnt[b]==16 (a full Phase A later --
//         in practice already satisfied), then Phase B as in v5.
// Deadlock analysis: every block signals unconditionally before any block
// waits; at full occupancy (2/CU x 256 CU = 512) all blocks co-resident; at
// 1/CU the first 256 raws are exactly the complete sibling groups b&3 in
// {0,1} (raw = xcd + 8*((b&3)*16+i), xcd=b>>2). Spin is additionally BOUNDED
// (~1e9 cycles): a violated assumption surfaces as absmax-fail, not a hang.
// Frag layouts (m89/m97-verified): A/B lane=(m|n)=lane&15, k=quad*8+j;
// C/D col=lane&15, row=quad*4+reg.
// LDS: 5*9216 + 1024 + 4224 = 51328 B -> 2 blocks/CU.
// ---------------------------------------------------------------------------
__global__ __launch_bounds__(256, 2) void fused_kernel(const float* __restrict__ neigh,
                                                       const float* __restrict__ node,
                                                       const int* __restrict__ nbr,
                                                       u16* __restrict__ MT,
                                                       float* __restrict__ out,
                                                       float* __restrict__ Wpart,
                                                       int* __restrict__ cnt) {
    __shared__ u16 Xh[64][72];   // X hi (reused as M-chunk stage in Phase B)
    __shared__ u16 Xl[64][72];   // X lo
    __shared__ u16 Nh[64][72];   // node hi chunk [t][k]
    __shared__ u16 Nl[64][72];   // node lo chunk
    __shared__ u16 Ph[64][72];   // P bf16 [q][t]
    __shared__ float Wtmp[256];
    __shared__ float Msc[4][264];

    // XCD-aware mapping (bijection on [0,512); perf heuristic, fences give
    // correctness regardless of actual placement)
    int raw  = blockIdx.x;
    int xcd  = raw & 7;
    int slot = raw >> 3;
    int b    = (xcd << 2) + (slot >> 4);
    int i    = slot & 15;
    int q0   = i << 6;

    int tid  = threadIdx.x;
    int w    = tid >> 6;         // wave 0..3
    int lane = tid & 63;
    int quad = lane >> 4;
    int c    = lane & 15;

    // neighbors_number: int64 per reference; harness may upload int32.
    // Values in [1,16] so nbr[1]==0 <=> int64 (high word of elem 0).
    int nb = (nbr[1] == 0) ? nbr[2 * b] : nbr[b];
    float rscale = rsqrtf((float)nb);

    const float* neighb = neigh + (size_t)b * Nc * Tc * Hc;
    const float* Xg  = neighb + (size_t)q0 * Hc;
    const float* Ng  = node + (size_t)b * Tc * Hc;
    u16*         MTb = MT + (size_t)b * Hc * Tc;

    // ---- M-slice: wave w sums row t=4i+w over all 16 i' (one HBM pass) ----
    {
        int tr = 4 * i + w;
        const float* rp = neighb + (size_t)tr * Hc + lane * 4;
        float4 a = make_float4(0.f, 0.f, 0.f, 0.f);
#pragma unroll
        for (int ip = 0; ip < Nc; ip++) {
            float4 v = *(const float4*)(rp + (size_t)ip * Tc * Hc);
            a.x += v.x; a.y += v.y; a.z += v.z; a.w += v.w;
        }
        const float r = 1.0f / 16.0f;
        Msc[w][lane * 4 + 0] = a.x * r;
        Msc[w][lane * 4 + 1] = a.y * r;
        Msc[w][lane * 4 + 2] = a.z * r;
        Msc[w][lane * 4 + 3] = a.w * r;
    }
    __syncthreads();
    {   // tid = h: pack 4 t-values, agent-scope 8B store (device-visible)
        int h = tid;
        unsigned long long val =
            (unsigned long long)f2bf(Msc[0][h]) |
            ((unsigned long long)f2bf(Msc[1][h]) << 16) |
            ((unsigned long long)f2bf(Msc[2][h]) << 32) |
            ((unsigned long long)f2bf(Msc[3][h]) << 48);
        __hip_atomic_store((unsigned long long*)(MTb + (size_t)h * Tc + 4 * i),
                           val, __ATOMIC_RELAXED, __HIP_MEMORY_SCOPE_AGENT);
    }
    __syncthreads();             // all MT stores issued+drained (vmcnt)
    if (tid == 0) {
        __threadfence();         // agent-scope release (belt)
        __hip_atomic_fetch_add(&cnt[b], 1, __ATOMIC_RELEASE, __HIP_MEMORY_SCOPE_AGENT);
    }

    v4f acc[4];
#pragma unroll
    for (int nt = 0; nt < 4; nt++)
#pragma unroll
        for (int rg = 0; rg < 4; rg++) acc[nt][rg] = 0.f;

    // ---- Phase A: K=256 in chunks of 64 (v5-identical) ----
    for (int k0 = 0; k0 < Hc; k0 += 64) {
#pragma unroll
        for (int rep = 0; rep < 4; rep++) {
            int idx = rep * 256 + tid;
            int row = idx >> 4, c4 = idx & 15;
            float4 xv = *(const float4*)(Xg + (size_t)row * Hc + k0 + c4 * 4);
            ushort4 hs, ls;
            hs.x = f2bf(xv.x); ls.x = f2bf(xv.x - bf2f(hs.x));
            hs.y = f2bf(xv.y); ls.y = f2bf(xv.y - bf2f(hs.y));
            hs.z = f2bf(xv.z); ls.z = f2bf(xv.z - bf2f(hs.z));
            hs.w = f2bf(xv.w); ls.w = f2bf(xv.w - bf2f(hs.w));
            *(ushort4*)&Xh[row][c4 * 4] = hs;
            *(ushort4*)&Xl[row][c4 * 4] = ls;
        }
#pragma unroll
        for (int rep = 0; rep < 4; rep++) {
            int idx = rep * 256 + tid;
            int row = idx >> 4, c4 = idx & 15;
            float4 nv = *(const float4*)(Ng + (size_t)row * Hc + k0 + c4 * 4);
            ushort4 hs, ls;
            hs.x = f2bf(nv.x); ls.x = f2bf(nv.x - bf2f(hs.x));
            hs.y = f2bf(nv.y); ls.y = f2bf(nv.y - bf2f(hs.y));
            hs.z = f2bf(nv.z); ls.z = f2bf(nv.z - bf2f(hs.z));
            hs.w = f2bf(nv.w); ls.w = f2bf(nv.w - bf2f(hs.w));
            *(ushort4*)&Nh[row][c4 * 4] = hs;
            *(ushort4*)&Nl[row][c4 * 4] = ls;
        }
        __syncthreads();

#pragma unroll
        for (int ks = 0; ks < 64; ks += 32) {
            v8s ah = *(const v8s*)&Xh[w * 16 + c][ks + quad * 8];
            v8s al = *(const v8s*)&Xl[w * 16 + c][ks + quad * 8];
#pragma unroll
            for (int nt = 0; nt < 4; nt++) {
                v8s bh = *(const v8s*)&Nh[nt * 16 + c][ks + quad * 8];
                v8s bl = *(const v8s*)&Nl[nt * 16 + c][ks + quad * 8];
                acc[nt] = __builtin_amdgcn_mfma_f32_16x16x32_bf16(ah, bh, acc[nt], 0, 0, 0);
                acc[nt] = __builtin_amdgcn_mfma_f32_16x16x32_bf16(ah, bl, acc[nt], 0, 0, 0);
                acc[nt] = __builtin_amdgcn_mfma_f32_16x16x32_bf16(al, bh, acc[nt], 0, 0, 0);
            }
        }
        __syncthreads();
    }

    // ---- Softmax over t (C-layout: col = nt*16+c, row = w*16+quad*4+rg) ----
#pragma unroll
    for (int nt = 0; nt < 4; nt++)
#pragma unroll
        for (int rg = 0; rg < 4; rg++) acc[nt][rg] *= rscale;

#pragma unroll
    for (int rg = 0; rg < 4; rg++) {
        float m = fmaxf(fmaxf(acc[0][rg], acc[1][rg]), fmaxf(acc[2][rg], acc[3][rg]));
#pragma unroll
        for (int d = 1; d < 16; d <<= 1) m = fmaxf(m, __shfl_xor(m, d));
        float e0 = __expf(acc[0][rg] - m);
        float e1 = __expf(acc[1][rg] - m);
        float e2 = __expf(acc[2][rg] - m);
        float e3 = __expf(acc[3][rg] - m);
        float s = e0 + e1 + e2 + e3;
#pragma unroll
        for (int d = 1; d < 16; d <<= 1) s += __shfl_xor(s, d);
        float inv = 1.0f / s;
        acc[0][rg] = e0 * inv; acc[1][rg] = e1 * inv;
        acc[2][rg] = e2 * inv; acc[3][rg] = e3 * inv;
    }

    // Column sums for W: per lane partial over its 4 rows, reduce across quads.
#pragma unroll
    for (int nt = 0; nt < 4; nt++) {
        float cs = acc[nt][0] + acc[nt][1] + acc[nt][2] + acc[nt][3];
        cs += __shfl_xor(cs, 16);
        cs += __shfl_xor(cs, 32);
        if (quad == 0) Wtmp[w * 64 + nt * 16 + c] = cs;
    }

    // P -> LDS as bf16 (row = w*16+quad*4+rg, col = nt*16+c)
#pragma unroll
    for (int nt = 0; nt < 4; nt++)
#pragma unroll
        for (int rg = 0; rg < 4; rg++)
            Ph[w * 16 + quad * 4 + rg][nt * 16 + c] = f2bf(acc[nt][rg]);

    __syncthreads();

    if (tid < 64) {
        float s = Wtmp[tid] + Wtmp[64 + tid] + Wtmp[128 + tid] + Wtmp[192 + tid];
        Wpart[((size_t)b * Nc + i) * Tc + tid] = s;   // private slot, no atomics
    }

    // ---- wait for all 16 siblings' MT slices (usually already done) ----
    // BOUNDED spin: ~2^21 iters x ~512cy s_sleep ~= 0.4s >> any real wait.
    // If the co-residency assumption is ever violated we fall through and
    // fail absmax (diagnosable) instead of hanging the container.
    if (tid == 0) {
        int guard = 1 << 21;
        while (__hip_atomic_load(&cnt[b], __ATOMIC_ACQUIRE, __HIP_MEMORY_SCOPE_AGENT) < 16
               && --guard)
            __builtin_amdgcn_s_sleep(8);
    }
    __syncthreads();

    // ---- Phase B: out = P(64x64) @ M(64x256), bf16 MFMA, K=64 ----
    v8s pa0 = *(const v8s*)&Ph[w * 16 + c][quad * 8];
    v8s pa1 = *(const v8s*)&Ph[w * 16 + c][32 + quad * 8];

    for (int h0 = 0; h0 < Hc; h0 += 64) {
        // stage MT chunk (64h x 64t bf16) into Xh (Phase A done with it)
#pragma unroll
        for (int rep = 0; rep < 2; rep++) {
            int idx = rep * 256 + tid;
            int row = idx >> 3, c8 = idx & 7;
            *(uint4*)&Xh[row][c8 * 8] = *(const uint4*)(MTb + (size_t)(h0 + row) * Tc + c8 * 8);
        }
        __syncthreads();

        v4f oc[4];
#pragma unroll
        for (int ht = 0; ht < 4; ht++)
#pragma unroll
            for (int rg = 0; rg < 4; rg++) oc[ht][rg] = 0.f;

#pragma unroll
        for (int ht = 0; ht < 4; ht++) {
            v8s b0 = *(const v8s*)&Xh[ht * 16 + c][quad * 8];
            v8s b1 = *(const v8s*)&Xh[ht * 16 + c][32 + quad * 8];
            oc[ht] = __builtin_amdgcn_mfma_f32_16x16x32_bf16(pa0, b0, oc[ht], 0, 0, 0);
            oc[ht] = __builtin_amdgcn_mfma_f32_16x16x32_bf16(pa1, b1, oc[ht], 0, 0, 0);
        }

        float* ob = out + ((size_t)b * NTc + q0 + w * 16 + quad * 4) * Hc + h0 + c;
#pragma unroll
        for (int ht = 0; ht < 4; ht++)
#pragma unroll
            for (int rg = 0; rg < 4; rg++)
                ob[(size_t)rg * Hc + ht * 16] = oc[ht][rg];

        __syncthreads();   // before overwriting Xh next chunk
    }
}

// ---------------------------------------------------------------------------
// W[b,i,t] = (1/16) * sum_i' Wpart[b,i',t]  (independent of i)
// ---------------------------------------------------------------------------
__global__ __launch_bounds__(256) void wexp_kernel(const float* __restrict__ Wpart,
                                                   float* __restrict__ Wout) {
    int idx = blockIdx.x * 256 + threadIdx.x;   // over B*N*T = 32768
    int b = idx >> 10;
    int t = idx & 63;
    const float* wp = Wpart + (size_t)b * Nc * Tc + t;
    float s = 0.f;
#pragma unroll
    for (int ip = 0; ip < Nc; ip++) s += wp[ip * Tc];
    Wout[idx] = s * (1.0f / 16.0f);
}

// ---------------------------------------------------------------------------
extern "C" void kernel_launch(void* const* d_in, const int* in_sizes, int n_in,
                              void* d_out, int out_size, void* d_ws, size_t ws_size,
                              hipStream_t stream) {
    const float* node  = (const float*)d_in[0];   // (B,T,H)
    const float* neigh = (const float*)d_in[1];   // (B,N,T,H)
    const int*   nbr   = (const int*)d_in[2];     // (B,) int32/int64 (detected)

    float* out = (float*)d_out;                   // (B,NT,H) then W (B,N,T)

    u16*   MTw   = (u16*)d_ws;                              // [B][H][T] bf16 mean^T
    float* Wpart = (float*)(MTw + (size_t)Bc * Hc * Tc);    // [B][N][T] fp32 partials
    int*   cnt   = (int*)(Wpart + (size_t)Bc * Nc * Tc);    // [B] completion counters

    hipMemsetAsync(cnt, 0, Bc * sizeof(int), stream);
    fused_kernel<<<512, 256, 0, stream>>>(neigh, node, nbr, MTw, out, Wpart, cnt);
    wexp_kernel <<<128, 256, 0, stream>>>(Wpart, out + (size_t)Bc * NTc * Hc);
}

// Round 8
// 105.998 us; speedup vs baseline: 1.1985x; 1.1985x over previous
//
#include <hip/hip_runtime.h>

// Problem constants
#define Bc  32
#define Nc  16
#define Tc  64
#define Hc  256
#define NTc 1024   // N*T

typedef unsigned short u16;
using v8s = __attribute__((ext_vector_type(8))) short;   // 8 bf16 = 4 VGPRs (MFMA A/B frag)
using v4f = __attribute__((ext_vector_type(4))) float;   // MFMA C/D frag

// fp32 -> bf16 round-to-nearest-even (bit manip; inputs finite)
static __device__ __forceinline__ u16 f2bf(float x) {
    unsigned u = __float_as_uint(x);
    unsigned r = u + 0x7fffu + ((u >> 16) & 1u);
    return (u16)(r >> 16);
}
static __device__ __forceinline__ float bf2f(u16 h) {
    return __uint_as_float(((unsigned)h) << 16);
}

// ---------------------------------------------------------------------------
// Prep kernel, 256 blocks — M only:
//  MT[b,h,t] = bf16( (1/16) * sum_i neigh[b,i,t,h] )
//  one (b, 64-h chunk, 32-t chunk) per block -> full-GPU BW on the 33.5MB
//  neigh read. Side effect (measured r7): warms L3 so fused's neigh re-read
//  is L3-served (merged-kernel FETCH was only 21MB).
// ---------------------------------------------------------------------------
__global__ __launch_bounds__(256) void prep_kernel(const float* __restrict__ neigh,
                                                   u16* __restrict__ MT) {
    __shared__ float Ls[32][68];
    int bk = blockIdx.x, tid = threadIdx.x;

    int b  = bk >> 3;
    int sub = bk & 7;
    int h0 = (sub & 3) << 6;    // 4 h-chunks of 64
    int t0 = (sub >> 2) << 5;   // 2 t-chunks of 32
#pragma unroll
    for (int rep = 0; rep < 2; rep++) {
        int idx = rep * 256 + tid;          // over 32t x 16 c4 = 512
        int t = idx >> 4, c4 = idx & 15;
        const float4* p = (const float4*)(neigh + ((size_t)b * Nc * Tc + t0 + t) * Hc + h0) + c4;
        float4 a = make_float4(0.f, 0.f, 0.f, 0.f);
#pragma unroll
        for (int i = 0; i < Nc; i++) {
            float4 v = p[(size_t)i * (Tc * Hc / 4)];
            a.x += v.x; a.y += v.y; a.z += v.z; a.w += v.w;
        }
        const float r = 1.0f / 16.0f;
        Ls[t][c4 * 4 + 0] = a.x * r;
        Ls[t][c4 * 4 + 1] = a.y * r;
        Ls[t][c4 * 4 + 2] = a.z * r;
        Ls[t][c4 * 4 + 3] = a.w * r;
    }
    __syncthreads();
    // transpose-write bf16: MT[b][h0+h][t0 + 0..31]
#pragma unroll
    for (int rep = 0; rep < 2; rep++) {
        int idx = rep * 256 + tid;          // over 64h x 8 t4-groups = 512
        int h = idx >> 3, t4 = idx & 7;
        ushort4 o;
        o.x = f2bf(Ls[t4 * 4 + 0][h]);
        o.y = f2bf(Ls[t4 * 4 + 1][h]);
        o.z = f2bf(Ls[t4 * 4 + 2][h]);
        o.w = f2bf(Ls[t4 * 4 + 3][h]);
        *(ushort4*)(MT + ((size_t)b * Hc + h0 + h) * Tc + t0 + t4 * 4) = o;
    }
}

// ---------------------------------------------------------------------------
// Fused MFMA kernel (104.7us-proven v5):
//  - node chunk staged from fp32 directly (hi/lo split in staging; no NH/NL
//    workspace round-trip). node[b]=64KB, L2-resident for the 16 siblings.
//  - column sums stored to private Wpart[b][i][t] (no atomics, no init).
//  - chunked LDS pipeline, v0 barrier structure, softmax, Phase B per-chunk
//    MT staging.
// Frag layouts (m89/m97-verified): A/B lane=(m|n)=lane&15, k=quad*8+j;
// C/D col=lane&15, row=quad*4+reg.
// ---------------------------------------------------------------------------
__global__ __launch_bounds__(256, 2) void fused_kernel(const float* __restrict__ neigh,
                                                       const float* __restrict__ node,
                                                       const int* __restrict__ nbr,
                                                       const u16* __restrict__ MT,
                                                       float* __restrict__ out,
                                                       float* __restrict__ Wpart) {
    __shared__ u16 Xh[64][72];   // X hi (also reused as M-chunk stage in Phase B)
    __shared__ u16 Xl[64][72];   // X lo
    __shared__ u16 Nh[64][72];   // node hi chunk [t][k]
    __shared__ u16 Nl[64][72];   // node lo chunk
    __shared__ u16 Ph[64][72];   // P bf16 [q][t]
    __shared__ float Wtmp[256];

    int b  = blockIdx.x >> 4;
    int i  = blockIdx.x & 15;
    int q0 = i << 6;

    int tid  = threadIdx.x;
    int w    = tid >> 6;         // wave 0..3
    int lane = tid & 63;
    int quad = lane >> 4;
    int c    = lane & 15;

    // neighbors_number: int64 per reference; harness may upload int32.
    // Values in [1,16] so nbr[1]==0 <=> int64 (high word of elem 0).
    int nb = (nbr[1] == 0) ? nbr[2 * b] : nbr[b];
    float rscale = rsqrtf((float)nb);

    const float* Xg  = neigh + ((size_t)b * Nc * Tc + q0) * Hc;
    const float* Ng  = node + (size_t)b * Tc * Hc;
    const u16*   MTg = MT + (size_t)b * Hc * Tc;

    v4f acc[4];
#pragma unroll
    for (int nt = 0; nt < 4; nt++)
#pragma unroll
        for (int rg = 0; rg < 4; rg++) acc[nt][rg] = 0.f;

    // ---- Phase A: K=256 in chunks of 64 ----
    for (int k0 = 0; k0 < Hc; k0 += 64) {
        // stage X chunk (64q x 64k fp32 -> hi/lo bf16)
#pragma unroll
        for (int rep = 0; rep < 4; rep++) {
            int idx = rep * 256 + tid;
            int row = idx >> 4, c4 = idx & 15;
            float4 xv = *(const float4*)(Xg + (size_t)row * Hc + k0 + c4 * 4);
            ushort4 hs, ls;
            hs.x = f2bf(xv.x); ls.x = f2bf(xv.x - bf2f(hs.x));
            hs.y = f2bf(xv.y); ls.y = f2bf(xv.y - bf2f(hs.y));
            hs.z = f2bf(xv.z); ls.z = f2bf(xv.z - bf2f(hs.z));
            hs.w = f2bf(xv.w); ls.w = f2bf(xv.w - bf2f(hs.w));
            *(ushort4*)&Xh[row][c4 * 4] = hs;
            *(ushort4*)&Xl[row][c4 * 4] = ls;
        }
        // stage node chunk (fp32 -> hi/lo bf16; L2-resident source)
#pragma unroll
        for (int rep = 0; rep < 4; rep++) {
            int idx = rep * 256 + tid;
            int row = idx >> 4, c4 = idx & 15;
            float4 nv = *(const float4*)(Ng + (size_t)row * Hc + k0 + c4 * 4);
            ushort4 hs, ls;
            hs.x = f2bf(nv.x); ls.x = f2bf(nv.x - bf2f(hs.x));
            hs.y = f2bf(nv.y); ls.y = f2bf(nv.y - bf2f(hs.y));
            hs.z = f2bf(nv.z); ls.z = f2bf(nv.z - bf2f(hs.z));
            hs.w = f2bf(nv.w); ls.w = f2bf(nv.w - bf2f(hs.w));
            *(ushort4*)&Nh[row][c4 * 4] = hs;
            *(ushort4*)&Nl[row][c4 * 4] = ls;
        }
        __syncthreads();

#pragma unroll
        for (int ks = 0; ks < 64; ks += 32) {
            v8s ah = *(const v8s*)&Xh[w * 16 + c][ks + quad * 8];
            v8s al = *(const v8s*)&Xl[w * 16 + c][ks + quad * 8];
#pragma unroll
            for (int nt = 0; nt < 4; nt++) {
                v8s bh = *(const v8s*)&Nh[nt * 16 + c][ks + quad * 8];
                v8s bl = *(const v8s*)&Nl[nt * 16 + c][ks + quad * 8];
                acc[nt] = __builtin_amdgcn_mfma_f32_16x16x32_bf16(ah, bh, acc[nt], 0, 0, 0);
                acc[nt] = __builtin_amdgcn_mfma_f32_16x16x32_bf16(ah, bl, acc[nt], 0, 0, 0);
                acc[nt] = __builtin_amdgcn_mfma_f32_16x16x32_bf16(al, bh, acc[nt], 0, 0, 0);
            }
        }
        __syncthreads();
    }

    // ---- Softmax over t (C-layout: col = nt*16+c, row = w*16+quad*4+rg) ----
#pragma unroll
    for (int nt = 0; nt < 4; nt++)
#pragma unroll
        for (int rg = 0; rg < 4; rg++) acc[nt][rg] *= rscale;

#pragma unroll
    for (int rg = 0; rg < 4; rg++) {
        float m = fmaxf(fmaxf(acc[0][rg], acc[1][rg]), fmaxf(acc[2][rg], acc[3][rg]));
#pragma unroll
        for (int d = 1; d < 16; d <<= 1) m = fmaxf(m, __shfl_xor(m, d));
        float e0 = __expf(acc[0][rg] - m);
        float e1 = __expf(acc[1][rg] - m);
        float e2 = __expf(acc[2][rg] - m);
        float e3 = __expf(acc[3][rg] - m);
        float s = e0 + e1 + e2 + e3;
#pragma unroll
        for (int d = 1; d < 16; d <<= 1) s += __shfl_xor(s, d);
        float inv = 1.0f / s;
        acc[0][rg] = e0 * inv; acc[1][rg] = e1 * inv;
        acc[2][rg] = e2 * inv; acc[3][rg] = e3 * inv;
    }

    // Column sums for W: per lane partial over its 4 rows, reduce across quads.
#pragma unroll
    for (int nt = 0; nt < 4; nt++) {
        float cs = acc[nt][0] + acc[nt][1] + acc[nt][2] + acc[nt][3];
        cs += __shfl_xor(cs, 16);
        cs += __shfl_xor(cs, 32);
        if (quad == 0) Wtmp[w * 64 + nt * 16 + c] = cs;
    }

    // P -> LDS as bf16 (row = w*16+quad*4+rg, col = nt*16+c)
#pragma unroll
    for (int nt = 0; nt < 4; nt++)
#pragma unroll
        for (int rg = 0; rg < 4; rg++)
            Ph[w * 16 + quad * 4 + rg][nt * 16 + c] = f2bf(acc[nt][rg]);

    __syncthreads();

    if (tid < 64) {
        float s = Wtmp[tid] + Wtmp[64 + tid] + Wtmp[128 + tid] + Wtmp[192 + tid];
        Wpart[((size_t)b * Nc + i) * Tc + tid] = s;   // private slot, no atomics
    }

    // ---- Phase B: out = P(64x64) @ M(64x256), bf16 MFMA, K=64 ----
    v8s pa0 = *(const v8s*)&Ph[w * 16 + c][quad * 8];
    v8s pa1 = *(const v8s*)&Ph[w * 16 + c][32 + quad * 8];

    for (int h0 = 0; h0 < Hc; h0 += 64) {
        // stage MT chunk (64h x 64t bf16) into Xh (Phase A done with it)
#pragma unroll
        for (int rep = 0; rep < 2; rep++) {
            int idx = rep * 256 + tid;
            int row = idx >> 3, c8 = idx & 7;
            *(uint4*)&Xh[row][c8 * 8] = *(const uint4*)(MTg + (size_t)(h0 + row) * Tc + c8 * 8);
        }
        __syncthreads();

        v4f oc[4];
#pragma unroll
        for (int ht = 0; ht < 4; ht++)
#pragma unroll
            for (int rg = 0; rg < 4; rg++) oc[ht][rg] = 0.f;

#pragma unroll
        for (int ht = 0; ht < 4; ht++) {
            v8s b0 = *(const v8s*)&Xh[ht * 16 + c][quad * 8];
            v8s b1 = *(const v8s*)&Xh[ht * 16 + c][32 + quad * 8];
            oc[ht] = __builtin_amdgcn_mfma_f32_16x16x32_bf16(pa0, b0, oc[ht], 0, 0, 0);
            oc[ht] = __builtin_amdgcn_mfma_f32_16x16x32_bf16(pa1, b1, oc[ht], 0, 0, 0);
        }

        float* ob = out + ((size_t)b * NTc + q0 + w * 16 + quad * 4) * Hc + h0 + c;
#pragma unroll
        for (int ht = 0; ht < 4; ht++)
#pragma unroll
            for (int rg = 0; rg < 4; rg++)
                ob[(size_t)rg * Hc + ht * 16] = oc[ht][rg];

        __syncthreads();   // before overwriting Xh next chunk
    }
}

// ---------------------------------------------------------------------------
// W[b,i,t] = (1/16) * sum_i' Wpart[b,i',t]  (independent of i)
// ---------------------------------------------------------------------------
__global__ __launch_bounds__(256) void wexp_kernel(const float* __restrict__ Wpart,
                                                   float* __restrict__ Wout) {
    int idx = blockIdx.x * 256 + threadIdx.x;   // over B*N*T = 32768
    int b = idx >> 10;
    int t = idx & 63;
    const float* wp = Wpart + (size_t)b * Nc * Tc + t;
    float s = 0.f;
#pragma unroll
    for (int ip = 0; ip < Nc; ip++) s += wp[ip * Tc];
    Wout[idx] = s * (1.0f / 16.0f);
}

// ---------------------------------------------------------------------------
extern "C" void kernel_launch(void* const* d_in, const int* in_sizes, int n_in,
                              void* d_out, int out_size, void* d_ws, size_t ws_size,
                              hipStream_t stream) {
    const float* node  = (const float*)d_in[0];   // (B,T,H)
    const float* neigh = (const float*)d_in[1];   // (B,N,T,H)
    const int*   nbr   = (const int*)d_in[2];     // (B,) int32/int64 (detected)

    float* out = (float*)d_out;                   // (B,NT,H) then W (B,N,T)

    u16*   MTw   = (u16*)d_ws;                              // [B][H][T] bf16 mean^T
    float* Wpart = (float*)(MTw + (size_t)Bc * Hc * Tc);    // [B][N][T] fp32 partials

    prep_kernel <<<256, 256, 0, stream>>>(neigh, MTw);
    fused_kernel<<<512, 256, 0, stream>>>(neigh, node, nbr, MTw, out, Wpart);
    wexp_kernel <<<128, 256, 0, stream>>>(Wpart, out + (size_t)Bc * NTc * Hc);
}